// Round 1
// baseline (422.782 us; speedup 1.0000x reference)
//
#include <hip/hip_runtime.h>

#define LC 256
#define LP 2000
#define NB 16
#define HD 1024
#define DD 64

typedef float f32x4 __attribute__((ext_vector_type(4)));
typedef _Float16 half8 __attribute__((ext_vector_type(8)));
typedef _Float16 half4 __attribute__((ext_vector_type(4)));

__device__ __forceinline__ float gelu_exact(float x) {
  return 0.5f * x * (1.0f + erff(x * 0.70710678118654752f));
}

// ---------------- W -> fp16, transposed to [n][k] ----------------
__global__ __launch_bounds__(256) void wtrans_kernel(
    const float* __restrict__ Wpc, const float* __restrict__ Wfc,
    const float* __restrict__ Wpp, const float* __restrict__ Wfp,
    _Float16* __restrict__ WtC, _Float16* __restrict__ WtP) {
  __shared__ float tile[64][65];
  const int kc = blockIdx.x;  // 16 k-chunks of 64
  const int m = blockIdx.y;   // 0:Wpc 1:Wfc 2:Wpp 3:Wfp
  const float* W = (m == 0) ? Wpc : (m == 1) ? Wfc : (m == 2) ? Wpp : Wfp;
  _Float16* dst = ((m < 2) ? WtC : WtP) + ((m & 1) ? (size_t)64 * HD : 0);
  const int t = threadIdx.x;
  const int c = t & 63, r4 = t >> 6;
  const int k0 = kc * 64;
#pragma unroll
  for (int rr = 0; rr < 16; ++rr) {
    int r = rr * 4 + r4;
    tile[r][c] = W[(size_t)(k0 + r) * DD + c];
  }
  __syncthreads();
#pragma unroll
  for (int rr = 0; rr < 16; ++rr) {
    int n = rr * 4 + r4;
    dst[(size_t)n * HD + k0 + c] = (_Float16)tile[c][n];
  }
}

// ---------------- projections: gelu(X@[W1|W2]+b)*mask ----------------
// grid: 64 compound tiles (rows 0..4095) + 500 protein tiles (rows 0..31999)
// block tile: 64 rows x 128 cols, K-tiles of 64; 4 waves as 2x2 (32x64 each)
__global__ __launch_bounds__(256) void proj_kernel(
    const float* __restrict__ comp, const float* __restrict__ prot,
    const _Float16* __restrict__ WtC, const _Float16* __restrict__ WtP,
    const float* __restrict__ bpc, const float* __restrict__ bpp,
    const float* __restrict__ bfc, const float* __restrict__ bfp,
    const float* __restrict__ cmask, const float* __restrict__ pmask,
    float* __restrict__ o_pc, float* __restrict__ o_pp,
    float* __restrict__ o_fc, float* __restrict__ o_fp) {
  __shared__ __align__(16) _Float16 As[64 * 64];   // [row][k], swizzled
  __shared__ __align__(16) _Float16 Ws[128 * 64];  // [n][k],  swizzled

  const int bx = blockIdx.x;
  const float* A;
  const _Float16* Wt;
  const float *b1, *b2, *mk;
  float *o1, *o2;
  if (bx < 64) {
    int row0 = bx * 64;
    A = comp + (size_t)row0 * HD;
    Wt = WtC; b1 = bpc; b2 = bfc;
    mk = cmask + row0;
    o1 = o_pc + (size_t)row0 * DD;
    o2 = o_fc + (size_t)row0 * DD;
  } else {
    int row0 = (bx - 64) * 64;
    A = prot + (size_t)row0 * HD;
    Wt = WtP; b1 = bpp; b2 = bfp;
    mk = pmask + row0;
    o1 = o_pp + (size_t)row0 * DD;
    o2 = o_fp + (size_t)row0 * DD;
  }

  const int t = threadIdx.x;
  const int lane = t & 63, wid = t >> 6;
  const int wr = wid >> 1, wc = wid & 1;
  const int l15 = lane & 15, l4 = lane >> 4;

  f32x4 acc[2][4];
#pragma unroll
  for (int m = 0; m < 2; ++m)
#pragma unroll
    for (int n = 0; n < 4; ++n) acc[m][n] = (f32x4){0.f, 0.f, 0.f, 0.f};

  for (int kt = 0; kt < 16; ++kt) {
    const int k0 = kt * 64;
    __syncthreads();
    // stage A tile (64x64 f32 -> fp16)
#pragma unroll
    for (int q = 0; q < 4; ++q) {
      int idx = q * 256 + t;
      int row = idx >> 4, kg = idx & 15;
      float4 v = *(const float4*)(A + (size_t)row * HD + k0 + kg * 4);
      half4 h = {(_Float16)v.x, (_Float16)v.y, (_Float16)v.z, (_Float16)v.w};
      int ofs = (row * 128 + kg * 8) ^ ((row & 7) << 4);
      *(half4*)((char*)As + ofs) = h;
    }
    // stage W tile (128n x 64k fp16, already [n][k] in global)
#pragma unroll
    for (int q = 0; q < 4; ++q) {
      int idx = q * 256 + t;
      int n = idx >> 3, kg = idx & 7;
      uint4 v = *(const uint4*)(Wt + (size_t)n * HD + k0 + kg * 8);
      int ofs = (n * 128 + kg * 16) ^ ((n & 7) << 4);
      *(uint4*)((char*)Ws + ofs) = v;
    }
    __syncthreads();
#pragma unroll
    for (int kk = 0; kk < 2; ++kk) {
      const int kb2 = (kk * 32 + l4 * 8) * 2;  // byte offset of 8-elem k-frag
      half8 af[2], wf[4];
#pragma unroll
      for (int m = 0; m < 2; ++m) {
        int row = wr * 32 + m * 16 + l15;
        af[m] = *(const half8*)((const char*)As + ((row * 128 + kb2) ^ ((row & 7) << 4)));
      }
#pragma unroll
      for (int n = 0; n < 4; ++n) {
        int col = wc * 64 + n * 16 + l15;
        wf[n] = *(const half8*)((const char*)Ws + ((col * 128 + kb2) ^ ((col & 7) << 4)));
      }
#pragma unroll
      for (int m = 0; m < 2; ++m)
#pragma unroll
        for (int n = 0; n < 4; ++n)
          acc[m][n] = __builtin_amdgcn_mfma_f32_16x16x32_f16(af[m], wf[n], acc[m][n], 0, 0, 0);
    }
  }

  // epilogue: bias + exact gelu + row mask, split to the two output arrays
#pragma unroll
  for (int m = 0; m < 2; ++m) {
#pragma unroll
    for (int n = 0; n < 4; ++n) {
      int coll = wc * 64 + n * 16 + l15;  // 0..127
      float bias = (coll < DD) ? b1[coll] : b2[coll - DD];
      float* op = (coll < DD) ? (o1 + coll) : (o2 + (coll - DD));
#pragma unroll
      for (int r = 0; r < 4; ++r) {
        int rowl = wr * 32 + m * 16 + l4 * 4 + r;  // C/D: row=(lane>>4)*4+reg
        float x = acc[m][n][r] + bias;
        op[(size_t)rowl * DD] = gelu_exact(x) * mk[rowl];
      }
    }
  }
}

// ---------------- scores -> maps + row/col sums ----------------
// grid (jt=16, it=8, b=16); tile 32 i x 128 j; thread: 4i x 4j (j strided by 32)
__global__ __launch_bounds__(256) void scores_kernel(
    const float* __restrict__ pc, const float* __restrict__ pp,
    const float* __restrict__ pmw, const float* __restrict__ cmask,
    const float* __restrict__ pmask, float* __restrict__ maps,
    float* __restrict__ rowsum, float* __restrict__ colsum) {
  __shared__ __align__(16) float pcs[32 * 64];
  __shared__ __align__(16) float pps[128 * 68];
  __shared__ float colsum_s[128];

  const int jt = blockIdx.x, it = blockIdx.y, b = blockIdx.z;
  const int i0 = it * 32, j0 = jt * 128;
  const int t = threadIdx.x;

#pragma unroll
  for (int q = 0; q < 2; ++q) {
    int idx = q * 256 + t;
    int row = idx >> 4, kg = idx & 15;
    *(float4*)&pcs[row * 64 + kg * 4] =
        *(const float4*)(pc + (size_t)(b * LC + i0 + row) * DD + kg * 4);
  }
#pragma unroll
  for (int q = 0; q < 8; ++q) {
    int idx = q * 256 + t;
    int row = idx >> 4, kg = idx & 15;
    int j = j0 + row;
    float4 v = make_float4(0.f, 0.f, 0.f, 0.f);
    if (j < LP) v = *(const float4*)(pp + (size_t)(b * LP + j) * DD + kg * 4);
    *(float4*)&pps[row * 68 + kg * 4] = v;
  }
  if (t < 128) colsum_s[t] = 0.0f;
  __syncthreads();

  const int jg = t & 31, ig = t >> 5;  // ig 0..7
  float s[4][4] = {};
#pragma unroll
  for (int k4 = 0; k4 < 16; ++k4) {
    float4 av[4], bv[4];
#pragma unroll
    for (int ii = 0; ii < 4; ++ii)
      av[ii] = *(const float4*)&pcs[(ig * 4 + ii) * 64 + k4 * 4];
#pragma unroll
    for (int jj = 0; jj < 4; ++jj)
      bv[jj] = *(const float4*)&pps[(jg + jj * 32) * 68 + k4 * 4];
#pragma unroll
    for (int ii = 0; ii < 4; ++ii)
#pragma unroll
      for (int jj = 0; jj < 4; ++jj)
        s[ii][jj] += av[ii].x * bv[jj].x + av[ii].y * bv[jj].y +
                     av[ii].z * bv[jj].z + av[ii].w * bv[jj].w;
  }

  float cmv[4];
#pragma unroll
  for (int ii = 0; ii < 4; ++ii) cmv[ii] = cmask[b * LC + i0 + ig * 4 + ii];
  float rowpart[4] = {0.f, 0.f, 0.f, 0.f};
  float colpart[4] = {0.f, 0.f, 0.f, 0.f};
#pragma unroll
  for (int jj = 0; jj < 4; ++jj) {
    int j = j0 + jg + jj * 32;
    if (j < LP) {
      float pmv = pmask[b * LP + j];
#pragma unroll
      for (int ii = 0; ii < 4; ++ii) {
        int i = i0 + ig * 4 + ii;
        size_t base = (size_t)(b * LC + i) * LP + j;
        float sc = s[ii][jj];
        float sm = sc * pmw[base];
        rowpart[ii] += sm;
        colpart[jj] += sm;
        maps[base] = (1.0f / (1.0f + expf(-sc))) * cmv[ii] * pmv;
      }
    }
  }
  // row sums: reduce over the 32 lanes (same 4 i's) of each half-wave
#pragma unroll
  for (int off = 16; off > 0; off >>= 1)
#pragma unroll
    for (int ii = 0; ii < 4; ++ii)
      rowpart[ii] += __shfl_xor(rowpart[ii], off, 32);
  if ((t & 31) == 0)
#pragma unroll
    for (int ii = 0; ii < 4; ++ii)
      atomicAdd(&rowsum[b * LC + i0 + ig * 4 + ii], rowpart[ii]);
  // col sums: fold the two half-waves, then LDS, then global
#pragma unroll
  for (int jj = 0; jj < 4; ++jj)
    colpart[jj] += __shfl_xor(colpart[jj], 32, 64);
  if ((t & 63) < 32)
#pragma unroll
    for (int jj = 0; jj < 4; ++jj)
      atomicAdd(&colsum_s[jg + jj * 32], colpart[jj]);
  __syncthreads();
  if (t < 128) {
    int j = j0 + t;
    if (j < LP) atomicAdd(&colsum[b * LP + j], colsum_s[t]);
  }
}

// ---------------- final vectors ----------------
__global__ __launch_bounds__(1024) void vec_kernel(
    const float* __restrict__ fc, const float* __restrict__ fp,
    const float* __restrict__ rowsum, const float* __restrict__ colsum,
    float* __restrict__ ovec) {
  __shared__ float red[16][64];
  const int b = blockIdx.x;
  const int d = threadIdx.x & 63, c = threadIdx.x >> 6;  // c 0..15
  float acc = 0.f;
  for (int i = c; i < LC; i += 16)
    acc += rowsum[b * LC + i] * fc[(size_t)(b * LC + i) * DD + d];
  red[c][d] = acc;
  __syncthreads();
  if (c == 0) {
    float ssum = 0.f;
#pragma unroll
    for (int r = 0; r < 16; ++r) ssum += red[r][d];
    ovec[b * 128 + d] = ssum;
  }
  __syncthreads();
  acc = 0.f;
  for (int j = c; j < LP; j += 16)
    acc += colsum[b * LP + j] * fp[(size_t)(b * LP + j) * DD + d];
  red[c][d] = acc;
  __syncthreads();
  if (c == 0) {
    float ssum = 0.f;
#pragma unroll
    for (int r = 0; r < 16; ++r) ssum += red[r][d];
    ovec[b * 128 + 64 + d] = ssum;
  }
}

extern "C" void kernel_launch(void* const* d_in, const int* in_sizes, int n_in,
                              void* d_out, int out_size, void* d_ws, size_t ws_size,
                              hipStream_t stream) {
  const float* prot  = (const float*)d_in[0];
  const float* pmask = (const float*)d_in[1];
  const float* comp  = (const float*)d_in[2];
  const float* cmask = (const float*)d_in[3];
  const float* pmw   = (const float*)d_in[4];
  const float* Wpc = (const float*)d_in[5];
  const float* bpc = (const float*)d_in[6];
  const float* Wpp = (const float*)d_in[7];
  const float* bpp = (const float*)d_in[8];
  const float* Wfc = (const float*)d_in[9];
  const float* bfc = (const float*)d_in[10];
  const float* Wfp = (const float*)d_in[11];
  const float* bfp = (const float*)d_in[12];

  float* out = (float*)d_out;
  float* o_vec  = out;                    // [16][128]
  float* o_maps = out + 2048;             // [16][256][2000]
  float* o_pc = out + 2048 + 8192000;     // [16][256][64]
  float* o_pp = o_pc + 262144;            // [16][2000][64]
  float* o_fc = o_pp + 2048000;           // [16][256][64]
  float* o_fp = o_fc + 262144;            // [16][2000][64]

  float* rowsum = (float*)d_ws;           // 4096
  float* colsum = rowsum + 4096;          // 32000
  _Float16* WtC;
  _Float16* WtP;
  if (ws_size >= (size_t)671744) {
    WtC = (_Float16*)((char*)d_ws + 147456);  // [128][1024] fp16
  } else {
    // fall back: stash Wt in the maps region (proj consumes it before scores writes maps)
    WtC = (_Float16*)o_maps;
  }
  WtP = WtC + 131072;

  hipMemsetAsync(d_ws, 0, 36096 * sizeof(float), stream);
  wtrans_kernel<<<dim3(16, 4), 256, 0, stream>>>(Wpc, Wfc, Wpp, Wfp, WtC, WtP);
  proj_kernel<<<564, 256, 0, stream>>>(comp, prot, WtC, WtP, bpc, bpp, bfc, bfp,
                                       cmask, pmask, o_pc, o_pp, o_fc, o_fp);
  scores_kernel<<<dim3(16, 8, 16), 256, 0, stream>>>(o_pc, o_pp, pmw, cmask, pmask,
                                                     o_maps, rowsum, colsum);
  vec_kernel<<<16, 1024, 0, stream>>>(o_fc, o_fp, rowsum, colsum, o_vec);
}

// Round 5
// 312.808 us; speedup vs baseline: 1.3516x; 1.3516x over previous
//
#include <hip/hip_runtime.h>

#define LC 256
#define LP 2000
#define NB 16
#define HD 1024
#define DD 64

typedef float f32x4 __attribute__((ext_vector_type(4)));
typedef _Float16 half8 __attribute__((ext_vector_type(8)));
typedef _Float16 half4 __attribute__((ext_vector_type(4)));

__device__ __forceinline__ float gelu_exact(float x) {
  return 0.5f * x * (1.0f + erff(x * 0.70710678118654752f));
}

__device__ __forceinline__ void gload_lds16(const _Float16* g, void* l) {
  __builtin_amdgcn_global_load_lds(
      (const __attribute__((address_space(1))) uint32_t*)g,
      (__attribute__((address_space(3))) uint32_t*)l, 16, 0, 0);
}

// ---------------- W -> fp16, transposed to [n][k] ----------------
__global__ __launch_bounds__(256) void wtrans_kernel(
    const float* __restrict__ Wpc, const float* __restrict__ Wfc,
    const float* __restrict__ Wpp, const float* __restrict__ Wfp,
    _Float16* __restrict__ WtC, _Float16* __restrict__ WtP) {
  __shared__ float tile[64][65];
  const int kc = blockIdx.x;  // 16 k-chunks of 64
  const int m = blockIdx.y;   // 0:Wpc 1:Wfc 2:Wpp 3:Wfp
  const float* W = (m == 0) ? Wpc : (m == 1) ? Wfc : (m == 2) ? Wpp : Wfp;
  _Float16* dst = ((m < 2) ? WtC : WtP) + ((m & 1) ? (size_t)64 * HD : 0);
  const int t = threadIdx.x;
  const int c = t & 63, r4 = t >> 6;
  const int k0 = kc * 64;
#pragma unroll
  for (int rr = 0; rr < 16; ++rr) {
    int r = rr * 4 + r4;
    tile[r][c] = W[(size_t)(k0 + r) * DD + c];
  }
  __syncthreads();
#pragma unroll
  for (int rr = 0; rr < 16; ++rr) {
    int n = rr * 4 + r4;
    dst[(size_t)n * HD + k0 + c] = (_Float16)tile[c][n];
  }
}

// ---------------- projections: gelu(X@[W1|W2]+b)*mask ----------------
#define LOAD_A(KT)                                                         \
  _Pragma("unroll") for (int q = 0; q < 4; ++q) {                          \
    int idx = q * 256 + t;                                                 \
    int row = idx >> 4, kg = idx & 15;                                     \
    areg[q] = *(const float4*)(A + (size_t)row * HD + (KT) * 64 + kg * 4); \
  }

#define WRITE_A(BUF)                                                       \
  _Pragma("unroll") for (int q = 0; q < 4; ++q) {                          \
    int idx = q * 256 + t;                                                 \
    int row = idx >> 4, kg = idx & 15;                                     \
    half4 h = {(_Float16)areg[q].x, (_Float16)areg[q].y,                   \
               (_Float16)areg[q].z, (_Float16)areg[q].w};                  \
    int ofs = (row * 128 + kg * 8) ^ ((row & 7) << 4);                     \
    *(half4*)((char*)As[BUF] + ofs) = h;                                   \
  }

#define LOAD_W(KT, BUF)                                      \
  _Pragma("unroll") for (int q = 0; q < 4; ++q) {            \
    gload_lds16(Wt + wOff[q] + (KT) * 64,                    \
                (char*)Ws[BUF] + wid * 4096 + q * 1024);     \
  }

#define COMPUTE(BUF)                                                          \
  _Pragma("unroll") for (int kk = 0; kk < 2; ++kk) {                          \
    const int kb2 = (kk * 32 + l4 * 8) * 2;                                   \
    half8 af[2], wf[4];                                                       \
    _Pragma("unroll") for (int m = 0; m < 2; ++m) {                           \
      int row = wr * 32 + m * 16 + l15;                                       \
      af[m] = *(const half8*)((const char*)As[BUF] +                          \
                              ((row * 128 + kb2) ^ ((row & 7) << 4)));        \
    }                                                                         \
    _Pragma("unroll") for (int n = 0; n < 4; ++n) {                           \
      int col = wc * 64 + n * 16 + l15;                                       \
      wf[n] = *(const half8*)((const char*)Ws[BUF] +                          \
                              ((col * 128 + kb2) ^ ((col & 7) << 4)));        \
    }                                                                         \
    _Pragma("unroll") for (int m = 0; m < 2; ++m)                             \
      _Pragma("unroll") for (int n = 0; n < 4; ++n)                           \
        acc[m][n] = __builtin_amdgcn_mfma_f32_16x16x32_f16(af[m], wf[n],      \
                                                           acc[m][n], 0, 0, 0); \
  }

__global__ __launch_bounds__(256, 3) void proj_kernel(
    const float* __restrict__ comp, const float* __restrict__ prot,
    const _Float16* __restrict__ WtC, const _Float16* __restrict__ WtP,
    const float* __restrict__ bpc, const float* __restrict__ bpp,
    const float* __restrict__ bfc, const float* __restrict__ bfp,
    const float* __restrict__ cmask, const float* __restrict__ pmask,
    float* __restrict__ o_pc, float* __restrict__ o_pp,
    float* __restrict__ o_fc, float* __restrict__ o_fp) {
  __shared__ __align__(16) _Float16 As[2][64 * 64];   // swizzled
  __shared__ __align__(16) _Float16 Ws[2][128 * 64];  // swizzled (linear dest)

  const int bx = blockIdx.x;
  const float* A;
  const _Float16* Wt;
  const float *b1, *b2, *mk;
  float *o1, *o2;
  if (bx < 64) {
    int row0 = bx * 64;
    A = comp + (size_t)row0 * HD;
    Wt = WtC; b1 = bpc; b2 = bfc;
    mk = cmask + row0;
    o1 = o_pc + (size_t)row0 * DD;
    o2 = o_fc + (size_t)row0 * DD;
  } else {
    int row0 = (bx - 64) * 64;
    A = prot + (size_t)row0 * HD;
    Wt = WtP; b1 = bpp; b2 = bfp;
    mk = pmask + row0;
    o1 = o_pp + (size_t)row0 * DD;
    o2 = o_fp + (size_t)row0 * DD;
  }

  const int t = threadIdx.x;
  const int lane = t & 63, wid = t >> 6;
  const int wr = wid >> 1, wc = wid & 1;
  const int l15 = lane & 15, l4 = lane >> 4;

  // per-lane pre-swizzled global element offsets for W (linear LDS dest)
  int wOff[4];
#pragma unroll
  for (int q = 0; q < 4; ++q) {
    int p = wid * 4096 + q * 1024 + lane * 16;  // physical byte in Ws tile
    int n = p >> 7;
    int l = p ^ ((n & 7) << 4);                 // logical byte
    wOff[q] = n * HD + ((l & 127) >> 1);        // element offset in Wt
  }

  f32x4 acc[2][4];
#pragma unroll
  for (int m = 0; m < 2; ++m)
#pragma unroll
    for (int n = 0; n < 4; ++n) acc[m][n] = (f32x4){0.f, 0.f, 0.f, 0.f};

  float4 areg[4];
  LOAD_A(0);
  LOAD_W(0, 0);
  WRITE_A(0);
  __syncthreads();

  int buf = 0;
#pragma unroll 2
  for (int kt = 0; kt < 16; ++kt) {
    if (kt < 15) {
      LOAD_A(kt + 1);
      LOAD_W(kt + 1, buf ^ 1);
    }
    COMPUTE(buf);
    if (kt < 15) { WRITE_A(buf ^ 1); }
    __syncthreads();
    buf ^= 1;
  }

  // epilogue: bias + exact gelu + row mask
#pragma unroll
  for (int m = 0; m < 2; ++m) {
#pragma unroll
    for (int n = 0; n < 4; ++n) {
      int coll = wc * 64 + n * 16 + l15;  // 0..127
      float bias = (coll < DD) ? b1[coll] : b2[coll - DD];
      float* op = (coll < DD) ? (o1 + coll) : (o2 + (coll - DD));
#pragma unroll
      for (int r = 0; r < 4; ++r) {
        int rowl = wr * 32 + m * 16 + l4 * 4 + r;
        float x = acc[m][n][r] + bias;
        op[(size_t)rowl * DD] = gelu_exact(x) * mk[rowl];
      }
    }
  }
}

// ---------------- scores -> maps + row/col sums (MFMA) ----------------
// grid (jt=16, it=4, b=16); tile 64 i x 128 j; 4 waves as 2x2 (32x64 each)
__global__ __launch_bounds__(256, 4) void scores_kernel(
    const float* __restrict__ pc, const float* __restrict__ pp,
    const float* __restrict__ pmw, const float* __restrict__ cmask,
    const float* __restrict__ pmask, float* __restrict__ maps,
    float* __restrict__ rowsum, float* __restrict__ colsum) {
  __shared__ __align__(16) _Float16 pcs[64 * 64];   // [i][k] swizzled
  __shared__ __align__(16) _Float16 pps[128 * 64];  // [j][k] swizzled
  __shared__ float rsum_s[64];
  __shared__ float csum_s[128];

  const int jt = blockIdx.x, it = blockIdx.y, b = blockIdx.z;
  const int i0 = it * 64, j0 = jt * 128;
  const int t = threadIdx.x;
  const int lane = t & 63, wid = t >> 6;
  const int l15 = lane & 15, l4 = lane >> 4;
  const int wi = wid >> 1, wj = wid & 1;

  if (t < 64) rsum_s[t] = 0.f;
  else if (t < 192) csum_s[t - 64] = 0.f;

  // stage pc 64x64 fp32 -> fp16 swizzled
#pragma unroll
  for (int q = 0; q < 4; ++q) {
    int idx = q * 256 + t;
    int row = idx >> 4, kg = idx & 15;
    float4 v = *(const float4*)(pc + (size_t)(b * LC + i0 + row) * DD + kg * 4);
    half4 h = {(_Float16)v.x, (_Float16)v.y, (_Float16)v.z, (_Float16)v.w};
    int ofs = (row * 128 + kg * 8) ^ ((row & 7) << 4);
    *(half4*)((char*)pcs + ofs) = h;
  }
  // stage pp 128x64 fp32 -> fp16 swizzled (guard j<LP)
#pragma unroll
  for (int q = 0; q < 8; ++q) {
    int idx = q * 256 + t;
    int row = idx >> 4, kg = idx & 15;
    int j = j0 + row;
    float4 v = make_float4(0.f, 0.f, 0.f, 0.f);
    if (j < LP) v = *(const float4*)(pp + (size_t)(b * LP + j) * DD + kg * 4);
    half4 h = {(_Float16)v.x, (_Float16)v.y, (_Float16)v.z, (_Float16)v.w};
    int ofs = (row * 128 + kg * 8) ^ ((row & 7) << 4);
    *(half4*)((char*)pps + ofs) = h;
  }
  __syncthreads();

  f32x4 acc[2][4];
#pragma unroll
  for (int m = 0; m < 2; ++m)
#pragma unroll
    for (int n = 0; n < 4; ++n) acc[m][n] = (f32x4){0.f, 0.f, 0.f, 0.f};

#pragma unroll
  for (int kk = 0; kk < 2; ++kk) {
    const int kb2 = (kk * 32 + l4 * 8) * 2;
    half8 af[2], wf[4];
#pragma unroll
    for (int m = 0; m < 2; ++m) {
      int row = wi * 32 + m * 16 + l15;
      af[m] = *(const half8*)((const char*)pcs + ((row * 128 + kb2) ^ ((row & 7) << 4)));
    }
#pragma unroll
    for (int n = 0; n < 4; ++n) {
      int col = wj * 64 + n * 16 + l15;
      wf[n] = *(const half8*)((const char*)pps + ((col * 128 + kb2) ^ ((col & 7) << 4)));
    }
#pragma unroll
    for (int m = 0; m < 2; ++m)
#pragma unroll
      for (int n = 0; n < 4; ++n)
        acc[m][n] = __builtin_amdgcn_mfma_f32_16x16x32_f16(af[m], wf[n], acc[m][n], 0, 0, 0);
  }

  // masks
  float pmj[4];
  int jv[4];
#pragma unroll
  for (int n = 0; n < 4; ++n) {
    int j = j0 + wj * 64 + n * 16 + l15;
    jv[n] = (j < LP);
    pmj[n] = jv[n] ? pmask[b * LP + j] : 0.f;
  }
  float cmv[2][4];
#pragma unroll
  for (int m = 0; m < 2; ++m)
#pragma unroll
    for (int r = 0; r < 4; ++r)
      cmv[m][r] = cmask[b * LC + i0 + wi * 32 + m * 16 + l4 * 4 + r];

  float rp[2][4] = {};
  float cp[4] = {0.f, 0.f, 0.f, 0.f};
#pragma unroll
  for (int m = 0; m < 2; ++m) {
#pragma unroll
    for (int n = 0; n < 4; ++n) {
      if (jv[n]) {
        int i = i0 + wi * 32 + m * 16 + l4 * 4;
        int j = j0 + wj * 64 + n * 16 + l15;
        size_t base = (size_t)(b * LC + i) * LP + j;
#pragma unroll
        for (int r = 0; r < 4; ++r) {
          float sc = acc[m][n][r];
          float w = pmw[base + (size_t)r * LP];
          float sm = sc * w;
          rp[m][r] += sm;
          cp[n] += sm;
          float sg = 1.0f / (1.0f + __expf(-sc));
          maps[base + (size_t)r * LP] = sg * cmv[m][r] * pmj[n];
        }
      }
    }
  }

  // row sums: reduce over the 16 lanes sharing rows (l15 varies)
#pragma unroll
  for (int off = 1; off < 16; off <<= 1)
#pragma unroll
    for (int m = 0; m < 2; ++m)
#pragma unroll
      for (int r = 0; r < 4; ++r) rp[m][r] += __shfl_xor(rp[m][r], off);
  if (l15 == 0) {
#pragma unroll
    for (int m = 0; m < 2; ++m)
#pragma unroll
      for (int r = 0; r < 4; ++r)
        atomicAdd(&rsum_s[wi * 32 + m * 16 + l4 * 4 + r], rp[m][r]);
  }
  // col sums: reduce over the 4 lane groups sharing cols (l4 varies)
#pragma unroll
  for (int off = 16; off < 64; off <<= 1)
#pragma unroll
    for (int n = 0; n < 4; ++n) cp[n] += __shfl_xor(cp[n], off);
  if (l4 == 0) {
#pragma unroll
    for (int n = 0; n < 4; ++n)
      atomicAdd(&csum_s[wj * 64 + n * 16 + l15], cp[n]);
  }
  __syncthreads();
  if (t < 64) {
    atomicAdd(&rowsum[b * LC + i0 + t], rsum_s[t]);
  } else if (t < 192) {
    int j = j0 + (t - 64);
    if (j < LP) atomicAdd(&colsum[b * LP + j], csum_s[t - 64]);
  }
}

// ---------------- final vectors ----------------
// grid (9, 16): part 0 = compound; parts 1..8 = protein j-chunks of 250
__global__ __launch_bounds__(256) void vec_kernel(
    const float* __restrict__ fc, const float* __restrict__ fp,
    const float* __restrict__ rowsum, const float* __restrict__ colsum,
    float* __restrict__ ovec) {
  __shared__ float red[4][64];
  const int part = blockIdx.x;
  const int b = blockIdx.y;
  const int d = threadIdx.x & 63, c = threadIdx.x >> 6;
  float acc = 0.f;
  if (part == 0) {
    for (int i = c; i < LC; i += 4)
      acc += rowsum[b * LC + i] * fc[(size_t)(b * LC + i) * DD + d];
  } else {
    int j0 = (part - 1) * 250, j1 = j0 + 250;
    for (int j = j0 + c; j < j1; j += 4)
      acc += colsum[b * LP + j] * fp[(size_t)(b * LP + j) * DD + d];
  }
  red[c][d] = acc;
  __syncthreads();
  if (c == 0) {
    float s = red[0][d] + red[1][d] + red[2][d] + red[3][d];
    atomicAdd(&ovec[b * 128 + (part == 0 ? d : 64 + d)], s);
  }
}

extern "C" void kernel_launch(void* const* d_in, const int* in_sizes, int n_in,
                              void* d_out, int out_size, void* d_ws, size_t ws_size,
                              hipStream_t stream) {
  const float* prot  = (const float*)d_in[0];
  const float* pmask = (const float*)d_in[1];
  const float* comp  = (const float*)d_in[2];
  const float* cmask = (const float*)d_in[3];
  const float* pmw   = (const float*)d_in[4];
  const float* Wpc = (const float*)d_in[5];
  const float* bpc = (const float*)d_in[6];
  const float* Wpp = (const float*)d_in[7];
  const float* bpp = (const float*)d_in[8];
  const float* Wfc = (const float*)d_in[9];
  const float* bfc = (const float*)d_in[10];
  const float* Wfp = (const float*)d_in[11];
  const float* bfp = (const float*)d_in[12];

  float* out = (float*)d_out;
  float* o_vec  = out;                    // [16][128]
  float* o_maps = out + 2048;             // [16][256][2000]
  float* o_pc = out + 2048 + 8192000;     // [16][256][64]
  float* o_pp = o_pc + 262144;            // [16][2000][64]
  float* o_fc = o_pp + 2048000;           // [16][256][64]
  float* o_fp = o_fc + 262144;            // [16][2000][64]

  float* rowsum = (float*)d_ws;           // 4096 floats
  float* colsum = rowsum + 4096;          // 32000 floats
  _Float16* WtC;
  _Float16* WtP;
  if (ws_size >= (size_t)671744) {
    WtC = (_Float16*)((char*)d_ws + 147456);  // [128][1024] fp16 x2
  } else {
    // stash Wt in the maps region (proj consumes it before scores writes maps)
    WtC = (_Float16*)o_maps;
  }
  WtP = WtC + 131072;

  hipMemsetAsync(d_ws, 0, 36096 * sizeof(float), stream);
  hipMemsetAsync(d_out, 0, 2048 * sizeof(float), stream);
  wtrans_kernel<<<dim3(16, 4), 256, 0, stream>>>(Wpc, Wfc, Wpp, Wfp, WtC, WtP);
  proj_kernel<<<564, 256, 0, stream>>>(comp, prot, WtC, WtP, bpc, bpp, bfc, bfp,
                                       cmask, pmask, o_pc, o_pp, o_fc, o_fp);
  scores_kernel<<<dim3(16, 4, 16), 256, 0, stream>>>(o_pc, o_pp, pmw, cmask, pmask,
                                                     o_maps, rowsum, colsum);
  vec_kernel<<<dim3(9, 16), 256, 0, stream>>>(o_fc, o_fp, rowsum, colsum, o_vec);
}